// Round 2
// baseline (78.977 us; speedup 1.0000x reference)
//
#include <hip/hip_runtime.h>
#include <hip/hip_bf16.h>

// Problem constants
#define B 64
#define D 1024
#define H 1024
#define C 32           // number of chunks along D
#define L (D / C)      // chunk length = 32
#define BG 4           // batch rows per block
#define NBG (B / BG)   // 16 batch groups

// DPP quad-perm cross-lane (VALU-speed, no LDS)
__device__ __forceinline__ float dpp_xor1(float v) {
    int i = __builtin_bit_cast(int, v);
    i = __builtin_amdgcn_mov_dpp(i, 0xB1, 0xF, 0xF, true);  // quad_perm [1,0,3,2]
    return __builtin_bit_cast(float, i);
}
__device__ __forceinline__ float dpp_xor2(float v) {
    int i = __builtin_bit_cast(int, v);
    i = __builtin_amdgcn_mov_dpp(i, 0x4E, 0xF, 0xF, true);  // quad_perm [2,3,0,1]
    return __builtin_bit_cast(float, i);
}

// ---------------------------------------------------------------------------
// Kernel 0: transpose in_W [H, D] -> Wt [D, H]
// ---------------------------------------------------------------------------
__global__ void k_transpose(const float* __restrict__ in, float* __restrict__ out) {
    __shared__ float tile[32][33];
    int bx = blockIdx.x * 32;  // d-range
    int by = blockIdx.y * 32;  // h-range
    int tx = threadIdx.x;      // 0..31
    int ty = threadIdx.y;      // 0..7
    #pragma unroll
    for (int r = 0; r < 32; r += 8)
        tile[ty + r][tx] = in[(by + ty + r) * D + (bx + tx)];
    __syncthreads();
    #pragma unroll
    for (int r = 0; r < 32; r += 8)
        out[(bx + ty + r) * H + (by + tx)] = tile[tx][ty + r];
}

// ---------------------------------------------------------------------------
// Kernel 1: per-chunk rank-1 sums, BG batch rows per block.
// block = (c, bg): S[b,c,:] = sum_{j in chunk c} x[b,j]*Wt[j,:]
// ---------------------------------------------------------------------------
__global__ void __launch_bounds__(256)
k_chunk_sums(const float* __restrict__ x,
             const float* __restrict__ Wt,
             float* __restrict__ S) {
    int blk = blockIdx.x;
    int c  = blk / NBG;
    int bg = blk % NBG;
    int b0 = bg * BG;
    int tid = threadIdx.x;
    int h0 = tid * 4;

    // build per-b bitmasks of x over this chunk via ballot
    __shared__ unsigned int mlds[BG];
    float xv = 0.f;
    if (tid < BG * L) xv = x[(b0 + (tid >> 5)) * D + c * L + (tid & 31)];
    unsigned long long bal = __ballot(xv != 0.f);
    if (tid == 0)  { mlds[0] = (unsigned)bal; mlds[1] = (unsigned)(bal >> 32); }
    if (tid == 64) { mlds[2] = (unsigned)bal; mlds[3] = (unsigned)(bal >> 32); }
    __syncthreads();
    unsigned m[BG];
    #pragma unroll
    for (int b = 0; b < BG; ++b) m[b] = mlds[b];
    unsigned anym = m[0] | m[1] | m[2] | m[3];

    float4 acc[BG];
    #pragma unroll
    for (int b = 0; b < BG; ++b) acc[b] = make_float4(0.f, 0.f, 0.f, 0.f);

    #pragma unroll
    for (int j = 0; j < L; ++j) {
        unsigned bit = 1u << j;
        if (anym & bit) {   // wave-uniform branch
            float4 w = *reinterpret_cast<const float4*>(&Wt[(c * L + j) * H + h0]);
            #pragma unroll
            for (int b = 0; b < BG; ++b) {
                if (m[b] & bit) {
                    acc[b].x += w.x; acc[b].y += w.y;
                    acc[b].z += w.z; acc[b].w += w.w;
                }
            }
        }
    }
    #pragma unroll
    for (int b = 0; b < BG; ++b)
        *reinterpret_cast<float4*>(&S[((size_t)(b0 + b) * C + c) * H + h0]) = acc[b];
}

// ---------------------------------------------------------------------------
// Kernel 2: in-place exclusive scan over chunks
// ---------------------------------------------------------------------------
__global__ void k_scan(float* __restrict__ S) {
    int tid = blockIdx.x * blockDim.x + threadIdx.x;  // 0 .. B*H-1
    if (tid >= B * H) return;
    int b = tid / H;
    int h = tid % H;
    float run = 0.f;
    #pragma unroll
    for (int c = 0; c < C; ++c) {
        int idx = (b * C + c) * H + h;
        float v = S[idx];
        S[idx] = run;
        run += v;
    }
}

// ---------------------------------------------------------------------------
// Kernel 3: main NADE chain, BG batch rows per block, deferred reduction.
// block = (c, bg), 256 threads, 4 h per thread.
// Loop (no barriers): thread-local dot partials, quad-DPP reduce, keeper-lane
// register stash; a += x_i * Wt[i] (wave-uniform masks). Reduce + sigmoid once
// at the end.
// ---------------------------------------------------------------------------
__global__ void __launch_bounds__(256)
k_nade_main(const float* __restrict__ x,
            const float* __restrict__ Wt,
            const float* __restrict__ in_b,
            const float* __restrict__ h_W,
            const float* __restrict__ h_b,
            const float* __restrict__ P,   // exclusive chunk prefixes
            float* __restrict__ out) {
    int blk = blockIdx.x;
    int c  = blk / NBG;
    int bg = blk % NBG;
    int b0 = bg * BG;
    int tid = threadIdx.x;
    int h0 = tid * 4;
    int lane = tid & 63;
    int wv = tid >> 6;
    int ph = lane & 3;

    // per-b x bitmasks for this chunk
    __shared__ unsigned int mlds[BG];
    float xv = 0.f;
    if (tid < BG * L) xv = x[(b0 + (tid >> 5)) * D + c * L + (tid & 31)];
    unsigned long long bal = __ballot(xv != 0.f);
    if (tid == 0)  { mlds[0] = (unsigned)bal; mlds[1] = (unsigned)(bal >> 32); }
    if (tid == 64) { mlds[2] = (unsigned)bal; mlds[3] = (unsigned)(bal >> 32); }

    // a = prefix + in_b
    float4 ib = *reinterpret_cast<const float4*>(&in_b[h0]);
    float4 a[BG];
    #pragma unroll
    for (int b = 0; b < BG; ++b) {
        float4 pv = *reinterpret_cast<const float4*>(&P[((size_t)(b0 + b) * C + c) * H + h0]);
        a[b].x = pv.x + ib.x; a[b].y = pv.y + ib.y;
        a[b].z = pv.z + ib.z; a[b].w = pv.w + ib.w;
    }

    __syncthreads();
    unsigned m[BG];
    #pragma unroll
    for (int b = 0; b < BG; ++b) m[b] = mlds[b];
    unsigned anym = m[0] | m[1] | m[2] | m[3];

    float pr[BG][8];
    #pragma unroll
    for (int b = 0; b < BG; ++b)
        #pragma unroll
        for (int s = 0; s < 8; ++s) pr[b][s] = 0.f;

    #pragma unroll
    for (int il = 0; il < L; ++il) {
        int i = c * L + il;
        float4 w = *reinterpret_cast<const float4*>(&h_W[(size_t)i * H + h0]);
        #pragma unroll
        for (int b = 0; b < BG; ++b) {
            float p = fmaxf(a[b].x, 0.f) * w.x + fmaxf(a[b].y, 0.f) * w.y +
                      fmaxf(a[b].z, 0.f) * w.z + fmaxf(a[b].w, 0.f) * w.w;
            // quad (4-lane) reduce, VALU-only
            float t = p + dpp_xor1(p);
            t = t + dpp_xor2(t);
            // keeper lane (ph == il&3) stashes quad-sum for this il
            pr[b][il >> 2] = (ph == (il & 3)) ? t : pr[b][il >> 2];
        }
        unsigned bit = 1u << il;
        if (anym & bit) {   // wave-uniform
            float4 wv4 = *reinterpret_cast<const float4*>(&Wt[(size_t)i * H + h0]);
            #pragma unroll
            for (int b = 0; b < BG; ++b) {
                if (m[b] & bit) {
                    a[b].x += wv4.x; a[b].y += wv4.y;
                    a[b].z += wv4.z; a[b].w += wv4.w;
                }
            }
        }
    }

    // cross-quad reduce within wave: after butterflies, every lane holds the
    // full wave-sum for il = s*4 + (lane&3)
    #pragma unroll
    for (int b = 0; b < BG; ++b) {
        #pragma unroll
        for (int s = 0; s < 8; ++s) {
            float v = pr[b][s];
            v += __shfl_xor(v, 4, 64);
            v += __shfl_xor(v, 8, 64);
            v += __shfl_xor(v, 16, 64);
            v += __shfl_xor(v, 32, 64);
            pr[b][s] = v;
        }
    }

    __shared__ float red[4][BG][L];
    if (lane < 4) {
        #pragma unroll
        for (int b = 0; b < BG; ++b)
            #pragma unroll
            for (int s = 0; s < 8; ++s)
                red[wv][b][s * 4 + lane] = pr[b][s];
    }
    __syncthreads();

    if (tid < BG * L) {
        int b = tid >> 5;
        int il = tid & 31;
        int i = c * L + il;
        float t = red[0][b][il] + red[1][b][il] + red[2][b][il] + red[3][b][il]
                + h_b[i];
        out[(size_t)(b0 + b) * D + i] = 1.0f / (1.0f + expf(-t));
    }
}

// ---------------------------------------------------------------------------
extern "C" void kernel_launch(void* const* d_in, const int* in_sizes, int n_in,
                              void* d_out, int out_size, void* d_ws, size_t ws_size,
                              hipStream_t stream) {
    const float* x    = (const float*)d_in[0];  // [B, D]
    const float* in_W = (const float*)d_in[1];  // [H, D]
    const float* in_b = (const float*)d_in[2];  // [H]
    const float* h_W  = (const float*)d_in[3];  // [D, H]
    const float* h_b  = (const float*)d_in[4];  // [D]
    float* out = (float*)d_out;                 // [B, D]

    float* Wt = (float*)d_ws;                   // [D, H]  4 MB
    float* S  = Wt + (size_t)D * H;             // [B, C, H]  8 MB

    // 0: transpose in_W -> Wt
    dim3 tb(32, 8);
    dim3 tg(D / 32, H / 32);
    k_transpose<<<tg, tb, 0, stream>>>(in_W, Wt);

    // 1: chunk sums (BG batch rows per block)
    k_chunk_sums<<<C * NBG, 256, 0, stream>>>(x, Wt, S);

    // 2: exclusive scan over chunks (in place)
    k_scan<<<(B * H + 255) / 256, 256, 0, stream>>>(S);

    // 3: main serial chain (BG batch rows per block, deferred reduce)
    k_nade_main<<<C * NBG, 256, 0, stream>>>(x, Wt, in_b, h_W, h_b, S, out);
}

// Round 3
// 45.566 us; speedup vs baseline: 1.7333x; 1.7333x over previous
//
#include <hip/hip_runtime.h>
#include <hip/hip_bf16.h>

// Problem constants
#define B 64
#define D 1024
#define H 1024
#define C 32           // number of chunks along D
#define L (D / C)      // chunk length = 32

// DPP quad-perm cross-lane (VALU-speed, no LDS)
__device__ __forceinline__ float dpp_xor1(float v) {
    int i = __builtin_bit_cast(int, v);
    i = __builtin_amdgcn_mov_dpp(i, 0xB1, 0xF, 0xF, true);  // quad_perm [1,0,3,2]
    return __builtin_bit_cast(float, i);
}
__device__ __forceinline__ float dpp_xor2(float v) {
    int i = __builtin_bit_cast(int, v);
    i = __builtin_amdgcn_mov_dpp(i, 0x4E, 0xF, 0xF, true);  // quad_perm [2,3,0,1]
    return __builtin_bit_cast(float, i);
}

// ---------------------------------------------------------------------------
// Kernel 0: transpose in_W [H, D] -> Wt [D, H]
// ---------------------------------------------------------------------------
__global__ void k_transpose(const float* __restrict__ in, float* __restrict__ out) {
    __shared__ float tile[32][33];
    int bx = blockIdx.x * 32;  // d-range
    int by = blockIdx.y * 32;  // h-range
    int tx = threadIdx.x;      // 0..31
    int ty = threadIdx.y;      // 0..7
    #pragma unroll
    for (int r = 0; r < 32; r += 8)
        tile[ty + r][tx] = in[(by + ty + r) * D + (bx + tx)];
    __syncthreads();
    #pragma unroll
    for (int r = 0; r < 32; r += 8)
        out[(bx + ty + r) * H + (by + tx)] = tile[tx][ty + r];
}

// ---------------------------------------------------------------------------
// Kernel 1: per-chunk rank-1 sums. block = (b,c), 256 threads, 4 h per thread.
// S[b,c,:] = sum_{j in chunk c} x[b,j]*Wt[j,:]   (x is exactly {0,1})
// ---------------------------------------------------------------------------
__global__ void __launch_bounds__(256, 4)
k_chunk_sums(const float* __restrict__ x,
             const float* __restrict__ Wt,
             float* __restrict__ S) {
    int blk = blockIdx.x;
    int b = blk / C;
    int c = blk % C;
    int tid = threadIdx.x;
    int h0 = tid * 4;

    // x bitmask for this chunk via ballot (lanes 0..31 of wave 0)
    __shared__ unsigned mlds;
    float xv = (tid < L) ? x[b * D + c * L + tid] : 0.f;
    unsigned long long bal = __ballot(xv != 0.f);
    if (tid == 0) mlds = (unsigned)bal;
    __syncthreads();
    unsigned m = mlds;

    float4 acc = make_float4(0.f, 0.f, 0.f, 0.f);
    #pragma unroll
    for (int j = 0; j < L; ++j) {
        if (m & (1u << j)) {   // wave-uniform branch
            float4 w = *reinterpret_cast<const float4*>(&Wt[(size_t)(c * L + j) * H + h0]);
            acc.x += w.x; acc.y += w.y; acc.z += w.z; acc.w += w.w;
        }
    }
    *reinterpret_cast<float4*>(&S[((size_t)b * C + c) * H + h0]) = acc;
}

// ---------------------------------------------------------------------------
// Kernel 2: in-place exclusive scan over chunks
// ---------------------------------------------------------------------------
__global__ void k_scan(float* __restrict__ S) {
    int tid = blockIdx.x * blockDim.x + threadIdx.x;  // 0 .. B*H-1
    if (tid >= B * H) return;
    int b = tid / H;
    int h = tid % H;
    float run = 0.f;
    #pragma unroll
    for (int c = 0; c < C; ++c) {
        int idx = (b * C + c) * H + h;
        float v = S[idx];
        S[idx] = run;
        run += v;
    }
}

// ---------------------------------------------------------------------------
// Kernel 3: main NADE chain. block = (b,c), 256 threads, 4 h per thread.
// Barrier-free loop: thread-local dot partial, quad-DPP reduce, keeper-lane
// register stash; a += x_i * Wt[i] under a wave-uniform mask. All cross-quad/
// cross-wave reduction + sigmoid happen once after the loop.
// ---------------------------------------------------------------------------
__global__ void __launch_bounds__(256, 4)
k_nade_main(const float* __restrict__ x,
            const float* __restrict__ Wt,
            const float* __restrict__ in_b,
            const float* __restrict__ h_W,
            const float* __restrict__ h_b,
            const float* __restrict__ P,   // exclusive chunk prefixes
            float* __restrict__ out) {
    int blk = blockIdx.x;
    int b = blk / C;
    int c = blk % C;
    int tid = threadIdx.x;
    int h0 = tid * 4;
    int lane = tid & 63;
    int wv = tid >> 6;
    int ph = lane & 3;

    // x bitmask for this chunk
    __shared__ unsigned mlds;
    float xv = (tid < L) ? x[b * D + c * L + tid] : 0.f;
    unsigned long long bal = __ballot(xv != 0.f);
    if (tid == 0) mlds = (unsigned)bal;

    // a = prefix + in_b
    float4 pv = *reinterpret_cast<const float4*>(&P[((size_t)b * C + c) * H + h0]);
    float4 ib = *reinterpret_cast<const float4*>(&in_b[h0]);
    float4 a;
    a.x = pv.x + ib.x; a.y = pv.y + ib.y; a.z = pv.z + ib.z; a.w = pv.w + ib.w;

    __syncthreads();
    unsigned m = mlds;

    float pr[8];
    #pragma unroll
    for (int s = 0; s < 8; ++s) pr[s] = 0.f;

    #pragma unroll
    for (int il = 0; il < L; ++il) {
        int i = c * L + il;
        float4 w = *reinterpret_cast<const float4*>(&h_W[(size_t)i * H + h0]);
        float p = fmaxf(a.x, 0.f) * w.x + fmaxf(a.y, 0.f) * w.y +
                  fmaxf(a.z, 0.f) * w.z + fmaxf(a.w, 0.f) * w.w;
        // quad (4-lane) reduce, VALU-only
        float t = p + dpp_xor1(p);
        t = t + dpp_xor2(t);
        // keeper lane (ph == il&3) stashes the quad-sum for this il
        pr[il >> 2] = (ph == (il & 3)) ? t : pr[il >> 2];

        if (m & (1u << il)) {   // wave-uniform
            float4 wv4 = *reinterpret_cast<const float4*>(&Wt[(size_t)i * H + h0]);
            a.x += wv4.x; a.y += wv4.y; a.z += wv4.z; a.w += wv4.w;
        }
    }

    // cross-quad reduce within the wave: after the butterflies every lane
    // holds the full wave-sum for il = s*4 + (lane&3)
    #pragma unroll
    for (int s = 0; s < 8; ++s) {
        float v = pr[s];
        v += __shfl_xor(v, 4, 64);
        v += __shfl_xor(v, 8, 64);
        v += __shfl_xor(v, 16, 64);
        v += __shfl_xor(v, 32, 64);
        pr[s] = v;
    }

    __shared__ float red[4][L];
    if (lane < 4) {
        #pragma unroll
        for (int s = 0; s < 8; ++s)
            red[wv][s * 4 + lane] = pr[s];
    }
    __syncthreads();

    if (tid < L) {
        int i = c * L + tid;
        float t = red[0][tid] + red[1][tid] + red[2][tid] + red[3][tid] + h_b[i];
        out[(size_t)b * D + i] = 1.0f / (1.0f + expf(-t));
    }
}

// ---------------------------------------------------------------------------
extern "C" void kernel_launch(void* const* d_in, const int* in_sizes, int n_in,
                              void* d_out, int out_size, void* d_ws, size_t ws_size,
                              hipStream_t stream) {
    const float* x    = (const float*)d_in[0];  // [B, D]
    const float* in_W = (const float*)d_in[1];  // [H, D]
    const float* in_b = (const float*)d_in[2];  // [H]
    const float* h_W  = (const float*)d_in[3];  // [D, H]
    const float* h_b  = (const float*)d_in[4];  // [D]
    float* out = (float*)d_out;                 // [B, D]

    float* Wt = (float*)d_ws;                   // [D, H]  4 MB
    float* S  = Wt + (size_t)D * H;             // [B, C, H]  8 MB

    // 0: transpose in_W -> Wt
    dim3 tb(32, 8);
    dim3 tg(D / 32, H / 32);
    k_transpose<<<tg, tb, 0, stream>>>(in_W, Wt);

    // 1: chunk sums
    k_chunk_sums<<<B * C, 256, 0, stream>>>(x, Wt, S);

    // 2: exclusive scan over chunks (in place)
    k_scan<<<(B * H + 255) / 256, 256, 0, stream>>>(S);

    // 3: main serial chain (barrier-free deferred reduction)
    k_nade_main<<<B * C, 256, 0, stream>>>(x, Wt, in_b, h_W, h_b, S, out);
}